// Round 2
// baseline (1114.024 us; speedup 1.0000x reference)
//
#include <hip/hip_runtime.h>
#include <hip/hip_bf16.h>
#include <cmath>

// Problem constants (Qwen2 MoE block)
#define TT   1024   // tokens
#define HH   2048   // hidden
#define EE   16     // experts
#define KTOP 4      // top-k
#define IM   1408   // moe intermediate
#define ISHD 5632   // shared intermediate
#define BK   64     // K-slice staged in LDS

typedef __bf16 bf16x8 __attribute__((ext_vector_type(8)));
typedef __bf16 bf16x4 __attribute__((ext_vector_type(4)));
typedef float  f32x4  __attribute__((ext_vector_type(4)));

__device__ inline bf16x4 cvt4(float4 f) {
    bf16x4 r;
    r[0] = (__bf16)f.x; r[1] = (__bf16)f.y; r[2] = (__bf16)f.z; r[3] = (__bf16)f.w;
    return r;
}

// async global->LDS DMA, 16B per lane; LDS dest is wave-uniform base (+lane*16).
__device__ inline void lds_dma16(void* lds, const void* g) {
    __builtin_amdgcn_global_load_lds(
        (const __attribute__((address_space(1))) unsigned int*)g,
        (__attribute__((address_space(3))) unsigned int*)lds, 16, 0, 0);
}

#define WAITCNT(vm) asm volatile("s_waitcnt vmcnt(" #vm ") lgkmcnt(0)" ::: "memory")
#define BARRIER() do { __builtin_amdgcn_s_barrier(); __builtin_amdgcn_sched_barrier(0); } while (0)

// ---------------------------------------------------------------------------
// Kernel 0: convert x fp32 -> bf16 once (A-side of all gate/up GEMMs)
// ---------------------------------------------------------------------------
__global__ __launch_bounds__(256) void cvtx_kernel(
    const float* __restrict__ x, __bf16* __restrict__ xb) {
    const int i = (blockIdx.x * 256 + threadIdx.x) * 4;
    *(bf16x4*)(xb + i) = cvt4(*(const float4*)(x + i));
}

// ---------------------------------------------------------------------------
// Kernel 1: router (fp32 exact). One block per token.
// ---------------------------------------------------------------------------
__global__ __launch_bounds__(256) void router_kernel(
    const float* __restrict__ x, const float* __restrict__ wr,
    const float* __restrict__ wshg,
    float* __restrict__ out_logits, int* __restrict__ counts,
    int* __restrict__ topk_e, int* __restrict__ topk_slot,
    float* __restrict__ topk_w, float* __restrict__ sgate)
{
    const int t    = blockIdx.x;
    const int tid  = threadIdx.x;
    const int wave = tid >> 6;
    const int lane = tid & 63;

    __shared__ float logits[EE];
    __shared__ float sgv;

    const float* xrow = x + (size_t)t * HH;
    float4 xv[4][2];
#pragma unroll
    for (int c = 0; c < 4; c++) {
        xv[c][0] = *(const float4*)(xrow + c * 512 + lane * 8);
        xv[c][1] = *(const float4*)(xrow + c * 512 + lane * 8 + 4);
    }

#pragma unroll
    for (int j = 0; j < 4; j++) {
        const int e = wave * 4 + j;
        const float* wrow = wr + (size_t)e * HH;
        float s = 0.f;
#pragma unroll
        for (int c = 0; c < 4; c++) {
            float4 w0 = *(const float4*)(wrow + c * 512 + lane * 8);
            float4 w1 = *(const float4*)(wrow + c * 512 + lane * 8 + 4);
            s += xv[c][0].x * w0.x + xv[c][0].y * w0.y + xv[c][0].z * w0.z + xv[c][0].w * w0.w;
            s += xv[c][1].x * w1.x + xv[c][1].y * w1.y + xv[c][1].z * w1.z + xv[c][1].w * w1.w;
        }
        for (int off = 32; off > 0; off >>= 1) s += __shfl_down(s, off, 64);
        if (lane == 0) logits[e] = s;
    }
    if (wave == 0) {
        float s = 0.f;
#pragma unroll
        for (int c = 0; c < 4; c++) {
            float4 w0 = *(const float4*)(wshg + c * 512 + lane * 8);
            float4 w1 = *(const float4*)(wshg + c * 512 + lane * 8 + 4);
            s += xv[c][0].x * w0.x + xv[c][0].y * w0.y + xv[c][0].z * w0.z + xv[c][0].w * w0.w;
            s += xv[c][1].x * w1.x + xv[c][1].y * w1.y + xv[c][1].z * w1.z + xv[c][1].w * w1.w;
        }
        for (int off = 32; off > 0; off >>= 1) s += __shfl_down(s, off, 64);
        if (lane == 0) sgv = s;
    }
    __syncthreads();

    if (tid == 0) {
        float mx = -1e30f;
        for (int e = 0; e < EE; e++) {
            out_logits[t * EE + e] = logits[e];
            mx = fmaxf(mx, logits[e]);
        }
        float p[EE]; float den = 0.f;
        for (int e = 0; e < EE; e++) { p[e] = expf(logits[e] - mx); den += p[e]; }
        const float inv = 1.f / den;
        bool used[EE];
        for (int e = 0; e < EE; e++) used[e] = false;
        for (int k = 0; k < KTOP; k++) {
            int best = 0; float bv = -1.f;
            for (int e = 0; e < EE; e++)
                if (!used[e] && p[e] > bv) { bv = p[e]; best = e; }
            used[best] = true;
            int slot = atomicAdd(&counts[best], 1);
            topk_e[t * KTOP + k]    = best;
            topk_slot[t * KTOP + k] = slot;
            topk_w[t * KTOP + k]    = bv * inv;   // fp32 unrounded
        }
        sgate[t] = 1.f / (1.f + expf(-sgv));
    }
}

__global__ void scan_kernel(const int* __restrict__ counts,
                            int* __restrict__ offsets) {
    if (threadIdx.x == 0 && blockIdx.x == 0) {
        int a = 0;
        for (int e = 0; e < EE; e++) { offsets[e] = a; a += counts[e]; }
        offsets[EE] = a;
    }
}

__global__ __launch_bounds__(256) void scatter_kernel(
    const int* __restrict__ offsets, const int* __restrict__ topk_e,
    const int* __restrict__ topk_slot, const float* __restrict__ topk_w,
    int* __restrict__ tok_list, float* __restrict__ wlist)
{
    const int i = blockIdx.x * 256 + threadIdx.x;
    if (i < TT * KTOP) {
        const int e   = topk_e[i];
        const int pos = offsets[e] + topk_slot[i];
        tok_list[pos] = i >> 2;
        wlist[pos]    = topk_w[i];
    }
}

// ---------------------------------------------------------------------------
// Kernel 2/4: gate+up dual GEMM. BM=128, BN=64, BK=64.
// T4 pipeline: raw s_barrier + counted vmcnt (loads stay in flight across the
// barrier). 2-deep named-bank B prefetch. A via global_load_lds (dbuf LDS),
// XOR-chunk swizzle baked into the global source address (rule #21).
// T1: 1-D grid + chunked XCD swizzle, m-tile fastest (weight-panel siblings
// land on the same XCD L2).
// ---------------------------------------------------------------------------
__global__ __launch_bounds__(256) void gateup_kernel(
    const __bf16* __restrict__ xb, const float* __restrict__ wgate,
    const float* __restrict__ wup, const int* __restrict__ counts,
    const int* __restrict__ offsets, const int* __restrict__ tok_list,
    const float* __restrict__ wlist, __bf16* __restrict__ Gout, const int I)
{
    // XCD-chunked swizzle; decode with m-tile fastest
    const int nwg   = gridDim.x;           // divisible by 8
    const int chunk = nwg >> 3;
    const int bid   = blockIdx.x;
    const int orig  = (bid & 7) * chunk + (bid >> 3);
    const int mt    = orig & 7;            // TT/128 = 8 m-tiles
    const int rest  = orig >> 3;
    const int NX    = I >> 6;              // I/64 n-tiles
    const int nt    = rest % NX;
    const int e     = rest / NX;

    const int Ne   = counts ? counts[e]  : TT;
    const int base = counts ? offsets[e] : 0;
    const int m0 = mt * 128;
    if (m0 >= Ne) return;
    const int n0 = nt * 64;

    __shared__ __bf16 As[2][128][64];    // 32 KB, DMA-filled, swizzled content
    __shared__ __bf16 Bgs[2][64][64];    // 16 KB, swizzled
    __shared__ __bf16 Bus[2][64][64];    // 16 KB, swizzled

    const int tid  = threadIdx.x;
    const int wave = tid >> 6, lane = tid & 63;

    // A DMA: wave w, pass p covers rows [p*32+w*8, +8); lane l -> row +(l>>3),
    // chunk (l&7). Source chunk = (l&7) ^ (row&7).
    const int arw = lane >> 3;
    const int sc8 = ((lane & 7) ^ arw) * 8;
    const __bf16* agp[4];
#pragma unroll
    for (int p = 0; p < 4; p++) {
        const int row = p * 32 + wave * 8 + arw;
        const int sc  = min(m0 + row, Ne - 1);
        const int tok = tok_list ? tok_list[base + sc] : sc;
        agp[p] = xb + (size_t)tok * HH + sc8;
    }

    // B staging: 16 rows/pass x (16 thr x float4), 4 passes
    const int brow = tid >> 4;
    const int bc4  = tid & 15;
    const float* bgptr[4];
    const float* buptr[4];
#pragma unroll
    for (int p = 0; p < 4; p++) {
        const size_t off = ((size_t)e * I + n0 + p * 16 + brow) * HH + bc4 * 4;
        bgptr[p] = wgate + off;
        buptr[p] = wup   + off;
    }
    const int bwo = ((((bc4 >> 1) ^ (brow & 7)) << 3) | ((bc4 & 1) << 2));

    const int wm = wave >> 1, wn = wave & 1;
    const int q = lane >> 4, r = lane & 15;
    const int r7 = r & 7;

    f32x4 accg[4][2], accu[4][2];
#pragma unroll
    for (int i = 0; i < 4; i++)
#pragma unroll
        for (int j = 0; j < 2; j++) {
            accg[i][j] = (f32x4){0.f, 0.f, 0.f, 0.f};
            accu[i][j] = (f32x4){0.f, 0.f, 0.f, 0.f};
        }

    // two named register banks (rule #20: no runtime-indexed reg arrays)
    float4 bgv0[4], buv0[4], bgv1[4], buv1[4];

    auto loadB0 = [&](int kk) {
#pragma unroll
        for (int p = 0; p < 4; p++) {
            bgv0[p] = *(const float4*)(bgptr[p] + kk);
            buv0[p] = *(const float4*)(buptr[p] + kk);
        }
    };
    auto loadB1 = [&](int kk) {
#pragma unroll
        for (int p = 0; p < 4; p++) {
            bgv1[p] = *(const float4*)(bgptr[p] + kk);
            buv1[p] = *(const float4*)(buptr[p] + kk);
        }
    };
    auto writeB0 = [&](int buf) {
#pragma unroll
        for (int p = 0; p < 4; p++) {
            *(bf16x4*)&Bgs[buf][p * 16 + brow][bwo] = cvt4(bgv0[p]);
            *(bf16x4*)&Bus[buf][p * 16 + brow][bwo] = cvt4(buv0[p]);
        }
    };
    auto writeB1 = [&](int buf) {
#pragma unroll
        for (int p = 0; p < 4; p++) {
            *(bf16x4*)&Bgs[buf][p * 16 + brow][bwo] = cvt4(bgv1[p]);
            *(bf16x4*)&Bus[buf][p * 16 + brow][bwo] = cvt4(buv1[p]);
        }
    };
    auto issueA = [&](int buf, int kk) {
#pragma unroll
        for (int p = 0; p < 4; p++)
            lds_dma16(&As[buf][p * 32 + wave * 8][0], agp[p] + kk);
    };
    auto compute = [&](int buf) {
#pragma unroll
        for (int ks = 0; ks < BK; ks += 32) {
            const int cb = (ks >> 3) + q;
            bf16x8 af[4], bgf[2], buf2[2];
#pragma unroll
            for (int i = 0; i < 4; i++)
                af[i] = *(const bf16x8*)&As[buf][wm * 64 + i * 16 + r][(cb ^ r7) * 8];
#pragma unroll
            for (int j = 0; j < 2; j++) {
                bgf[j]  = *(const bf16x8*)&Bgs[buf][wn * 32 + j * 16 + r][(cb ^ r7) * 8];
                buf2[j] = *(const bf16x8*)&Bus[buf][wn * 32 + j * 16 + r][(cb ^ r7) * 8];
            }
#pragma unroll
            for (int i = 0; i < 4; i++)
#pragma unroll
                for (int j = 0; j < 2; j++) {
                    accg[i][j] = __builtin_amdgcn_mfma_f32_16x16x32_bf16(af[i], bgf[j],  accg[i][j], 0, 0, 0);
                    accu[i][j] = __builtin_amdgcn_mfma_f32_16x16x32_bf16(af[i], buf2[j], accu[i][j], 0, 0, 0);
                }
        }
    };

    constexpr int NS = HH / BK;   // 32 (even)
    // prologue: tiles 0 (LDS), 1 (bank1), 2 (bank0)
    loadB0(0); issueA(0, 0);
    writeB0(0);
    loadB1(BK);
    loadB0(2 * BK);
    WAITCNT(16);                 // drain A-DMA(0); L(t1)+L(t2)=16 stay in flight
    BARRIER();

#pragma unroll 1
    for (int s = 0; s < NS; s += 2) {
        // sub-step A: compute tile s (buf0); stage tile s+1 (buf1,bank1); load t s+3 (bank1)
        if (s + 1 < NS) { writeB1(1); issueA(1, (s + 1) * BK); }
        if (s + 3 < NS) loadB1((s + 3) * BK);
        compute(0);
        if (s + 1 < NS) {
            if (s + 3 < NS) WAITCNT(8); else WAITCNT(0);
            BARRIER();
            // sub-step B: compute tile s+1 (buf1); stage t s+2 (buf0,bank0); load t s+4
            if (s + 2 < NS) { writeB0(0); issueA(0, (s + 2) * BK); }
            if (s + 4 < NS) loadB0((s + 4) * BK);
            compute(1);
            if (s + 2 < NS) {
                if (s + 4 < NS) WAITCNT(8); else WAITCNT(0);
                BARRIER();
            }
        }
    }

#pragma unroll
    for (int i = 0; i < 4; i++)
#pragma unroll
        for (int reg = 0; reg < 4; reg++) {
            const int srow = m0 + wm * 64 + i * 16 + q * 4 + reg;
            if (srow < Ne) {
                const float w = wlist ? wlist[base + srow] : 1.f;
                __bf16* gp = Gout + (size_t)(base + srow) * I + n0 + wn * 32;
#pragma unroll
                for (int j = 0; j < 2; j++) {
                    float g = accg[i][j][reg];
                    float u = accu[i][j][reg];
                    float act = g / (1.f + expf(-g));
                    gp[j * 16 + r] = (__bf16)(act * u * w);
                }
            }
        }
}

// ---------------------------------------------------------------------------
// Kernel 3: expert down GEMM. BM=128, BN=128, BK=64. Same T4 pipeline.
// ---------------------------------------------------------------------------
__global__ __launch_bounds__(256) void down_kernel(
    const __bf16* __restrict__ G, const float* __restrict__ wd,
    const int* __restrict__ counts, const int* __restrict__ offsets,
    const int* __restrict__ tok_list, float* __restrict__ moeacc)
{
    const int nwg   = gridDim.x;           // 2048
    const int chunk = nwg >> 3;
    const int bid   = blockIdx.x;
    const int orig  = (bid & 7) * chunk + (bid >> 3);
    const int mt    = orig & 7;            // 8 m-tiles
    const int rest  = orig >> 3;
    const int nt    = rest & 15;           // HH/128 = 16
    const int e     = rest >> 4;

    const int Ne   = counts[e];
    const int base = offsets[e];
    const int m0 = mt * 128;
    if (m0 >= Ne) return;
    const int n0 = nt * 128;

    __shared__ __bf16 As[2][128][64];   // 32 KB
    __shared__ __bf16 Bs[2][128][64];   // 32 KB

    const int tid  = threadIdx.x;
    const int wave = tid >> 6, lane = tid & 63;

    const int arw = lane >> 3;
    const int sc8 = ((lane & 7) ^ arw) * 8;
    const __bf16* agp[4];
#pragma unroll
    for (int p = 0; p < 4; p++) {
        const int row = p * 32 + wave * 8 + arw;
        const int sc  = min(m0 + row, Ne - 1);
        agp[p] = G + (size_t)(base + sc) * IM + sc8;
    }

    const int brow = tid >> 4;
    const int bc4  = tid & 15;
    const float* bptr[8];
#pragma unroll
    for (int p = 0; p < 8; p++)
        bptr[p] = wd + ((size_t)e * HH + n0 + p * 16 + brow) * IM + bc4 * 4;
    const int bwo = ((((bc4 >> 1) ^ (brow & 7)) << 3) | ((bc4 & 1) << 2));

    const int wm = wave >> 1, wn = wave & 1;
    const int q = lane >> 4, r = lane & 15;
    const int r7 = r & 7;

    f32x4 acc[4][4];
#pragma unroll
    for (int i = 0; i < 4; i++)
#pragma unroll
        for (int j = 0; j < 4; j++) acc[i][j] = (f32x4){0.f, 0.f, 0.f, 0.f};

    float4 bv0[8], bv1[8];

    auto loadB0 = [&](int kk) {
#pragma unroll
        for (int p = 0; p < 8; p++) bv0[p] = *(const float4*)(bptr[p] + kk);
    };
    auto loadB1 = [&](int kk) {
#pragma unroll
        for (int p = 0; p < 8; p++) bv1[p] = *(const float4*)(bptr[p] + kk);
    };
    auto writeB0 = [&](int buf) {
#pragma unroll
        for (int p = 0; p < 8; p++)
            *(bf16x4*)&Bs[buf][p * 16 + brow][bwo] = cvt4(bv0[p]);
    };
    auto writeB1 = [&](int buf) {
#pragma unroll
        for (int p = 0; p < 8; p++)
            *(bf16x4*)&Bs[buf][p * 16 + brow][bwo] = cvt4(bv1[p]);
    };
    auto issueA = [&](int buf, int kk) {
#pragma unroll
        for (int p = 0; p < 4; p++)
            lds_dma16(&As[buf][p * 32 + wave * 8][0], agp[p] + kk);
    };
    auto compute = [&](int buf) {
#pragma unroll
        for (int ks = 0; ks < BK; ks += 32) {
            const int cb = (ks >> 3) + q;
            bf16x8 af[4], bf[4];
#pragma unroll
            for (int i = 0; i < 4; i++)
                af[i] = *(const bf16x8*)&As[buf][wm * 64 + i * 16 + r][(cb ^ r7) * 8];
#pragma unroll
            for (int j = 0; j < 4; j++)
                bf[j] = *(const bf16x8*)&Bs[buf][wn * 64 + j * 16 + r][(cb ^ r7) * 8];
#pragma unroll
            for (int i = 0; i < 4; i++)
#pragma unroll
                for (int j = 0; j < 4; j++)
                    acc[i][j] = __builtin_amdgcn_mfma_f32_16x16x32_bf16(af[i], bf[j], acc[i][j], 0, 0, 0);
        }
    };

    constexpr int NS = IM / BK;   // 22 (even)
    loadB0(0); issueA(0, 0);
    writeB0(0);
    loadB1(BK);
    loadB0(2 * BK);
    WAITCNT(16);
    BARRIER();

#pragma unroll 1
    for (int s = 0; s < NS; s += 2) {
        if (s + 1 < NS) { writeB1(1); issueA(1, (s + 1) * BK); }
        if (s + 3 < NS) loadB1((s + 3) * BK);
        compute(0);
        if (s + 1 < NS) {
            if (s + 3 < NS) WAITCNT(8); else WAITCNT(0);
            BARRIER();
            if (s + 2 < NS) { writeB0(0); issueA(0, (s + 2) * BK); }
            if (s + 4 < NS) loadB0((s + 4) * BK);
            compute(1);
            if (s + 2 < NS) {
                if (s + 4 < NS) WAITCNT(8); else WAITCNT(0);
                BARRIER();
            }
        }
    }

#pragma unroll
    for (int i = 0; i < 4; i++)
#pragma unroll
        for (int reg = 0; reg < 4; reg++) {
            const int srow = m0 + wm * 64 + i * 16 + q * 4 + reg;
            if (srow < Ne) {
                const int tok = tok_list[base + srow];
                float* mp = moeacc + (size_t)tok * HH + n0 + wn * 64;
#pragma unroll
                for (int j = 0; j < 4; j++)
                    atomicAdd(mp + j * 16 + r, acc[i][j][reg]);
            }
        }
}

// ---------------------------------------------------------------------------
// Kernel 5: shared down + sigmoid gate + combine. BM=128, BN=64, BK=64.
// Same T4 pipeline (L=4 loads/step -> vmcnt(4) steady).
// ---------------------------------------------------------------------------
__global__ __launch_bounds__(256) void shdown_kernel(
    const __bf16* __restrict__ S, const float* __restrict__ wsd,
    const float* __restrict__ moeacc, const float* __restrict__ sgate,
    float* __restrict__ out)
{
    const int nwg   = gridDim.x;           // 256
    const int chunk = nwg >> 3;
    const int bid   = blockIdx.x;
    const int orig  = (bid & 7) * chunk + (bid >> 3);
    const int mt    = orig & 7;
    const int nt    = orig >> 3;           // HH/64 = 32

    const int m0 = mt * 128;
    const int n0 = nt * 64;

    __shared__ __bf16 As[2][128][64];   // 32 KB
    __shared__ __bf16 Bs[2][64][64];    // 16 KB

    const int tid  = threadIdx.x;
    const int wave = tid >> 6, lane = tid & 63;

    const int arw = lane >> 3;
    const int sc8 = ((lane & 7) ^ arw) * 8;
    const __bf16* agp[4];
#pragma unroll
    for (int p = 0; p < 4; p++) {
        const int row = p * 32 + wave * 8 + arw;
        agp[p] = S + (size_t)(m0 + row) * ISHD + sc8;
    }

    const int brow = tid >> 4;
    const int bc4  = tid & 15;
    const float* bptr[4];
#pragma unroll
    for (int p = 0; p < 4; p++)
        bptr[p] = wsd + (size_t)(n0 + p * 16 + brow) * ISHD + bc4 * 4;
    const int bwo = ((((bc4 >> 1) ^ (brow & 7)) << 3) | ((bc4 & 1) << 2));

    const int wm = wave >> 1, wn = wave & 1;
    const int q = lane >> 4, r = lane & 15;
    const int r7 = r & 7;

    f32x4 acc[4][2];
#pragma unroll
    for (int i = 0; i < 4; i++)
#pragma unroll
        for (int j = 0; j < 2; j++) acc[i][j] = (f32x4){0.f, 0.f, 0.f, 0.f};

    float4 bv0[4], bv1[4];

    auto loadB0 = [&](int kk) {
#pragma unroll
        for (int p = 0; p < 4; p++) bv0[p] = *(const float4*)(bptr[p] + kk);
    };
    auto loadB1 = [&](int kk) {
#pragma unroll
        for (int p = 0; p < 4; p++) bv1[p] = *(const float4*)(bptr[p] + kk);
    };
    auto writeB0 = [&](int buf) {
#pragma unroll
        for (int p = 0; p < 4; p++)
            *(bf16x4*)&Bs[buf][p * 16 + brow][bwo] = cvt4(bv0[p]);
    };
    auto writeB1 = [&](int buf) {
#pragma unroll
        for (int p = 0; p < 4; p++)
            *(bf16x4*)&Bs[buf][p * 16 + brow][bwo] = cvt4(bv1[p]);
    };
    auto issueA = [&](int buf, int kk) {
#pragma unroll
        for (int p = 0; p < 4; p++)
            lds_dma16(&As[buf][p * 32 + wave * 8][0], agp[p] + kk);
    };
    auto compute = [&](int buf) {
#pragma unroll
        for (int ks = 0; ks < BK; ks += 32) {
            const int cb = (ks >> 3) + q;
            bf16x8 af[4], bf[2];
#pragma unroll
            for (int i = 0; i < 4; i++)
                af[i] = *(const bf16x8*)&As[buf][wm * 64 + i * 16 + r][(cb ^ r7) * 8];
#pragma unroll
            for (int j = 0; j < 2; j++)
                bf[j] = *(const bf16x8*)&Bs[buf][wn * 32 + j * 16 + r][(cb ^ r7) * 8];
#pragma unroll
            for (int i = 0; i < 4; i++)
#pragma unroll
                for (int j = 0; j < 2; j++)
                    acc[i][j] = __builtin_amdgcn_mfma_f32_16x16x32_bf16(af[i], bf[j], acc[i][j], 0, 0, 0);
        }
    };

    constexpr int NS = ISHD / BK;   // 88 (even)
    loadB0(0); issueA(0, 0);
    writeB0(0);
    loadB1(BK);
    loadB0(2 * BK);
    WAITCNT(8);                    // drain A-DMA; L(t1)+L(t2)=8 in flight
    BARRIER();

#pragma unroll 1
    for (int s = 0; s < NS; s += 2) {
        if (s + 1 < NS) { writeB1(1); issueA(1, (s + 1) * BK); }
        if (s + 3 < NS) loadB1((s + 3) * BK);
        compute(0);
        if (s + 1 < NS) {
            if (s + 3 < NS) WAITCNT(4); else WAITCNT(0);
            BARRIER();
            if (s + 2 < NS) { writeB0(0); issueA(0, (s + 2) * BK); }
            if (s + 4 < NS) loadB0((s + 4) * BK);
            compute(1);
            if (s + 2 < NS) {
                if (s + 4 < NS) WAITCNT(4); else WAITCNT(0);
                BARRIER();
            }
        }
    }

#pragma unroll
    for (int i = 0; i < 4; i++)
#pragma unroll
        for (int reg = 0; reg < 4; reg++) {
            const int t  = m0 + wm * 64 + i * 16 + q * 4 + reg;
            const float sg = sgate[t];
            const float* mp = moeacc + (size_t)t * HH + n0 + wn * 32;
            float* op = out + (size_t)t * HH + n0 + wn * 32;
#pragma unroll
            for (int j = 0; j < 2; j++)
                op[j * 16 + r] = mp[j * 16 + r] + sg * acc[i][j][reg];
        }
}

// ---------------------------------------------------------------------------
extern "C" void kernel_launch(void* const* d_in, const int* in_sizes, int n_in,
                              void* d_out, int out_size, void* d_ws, size_t ws_size,
                              hipStream_t stream) {
    const float* x    = (const float*)d_in[0];
    const float* wr   = (const float*)d_in[1];
    const float* wg   = (const float*)d_in[2];
    const float* wu   = (const float*)d_in[3];
    const float* wd   = (const float*)d_in[4];
    const float* wsg  = (const float*)d_in[5];
    const float* wsu  = (const float*)d_in[6];
    const float* wsd  = (const float*)d_in[7];
    const float* wshg = (const float*)d_in[8];

    float* out        = (float*)d_out;
    float* out_logits = out + (size_t)TT * HH;

    // workspace layout (~23.1 MiB; G and S alias: G dies before S is born)
    char* ws = (char*)d_ws;
    int*    counts    = (int*)(ws + 0);
    int*    offsets   = (int*)(ws + 256);
    int*    topk_e    = (int*)(ws + 512);
    int*    topk_slot = (int*)(ws + 512 + 16384);
    float*  topk_w    = (float*)(ws + 512 + 32768);
    float*  sgate     = (float*)(ws + 512 + 49152);
    int*    tok_list  = (int*)(ws + 512 + 53248);
    float*  wlist     = (float*)(ws + 512 + 69632);
    __bf16* xb        = (__bf16*)(ws + 86528);                 // 4 MB [TT][HH] bf16
    float*  moeacc    = (float*)(ws + 86528 + 4194304);        // 8 MB [TT][HH] f32
    char*   GS        = (char*)moeacc + (size_t)TT * HH * 4;   // 11.5 MB
    __bf16* G = (__bf16*)GS;   // compact [TT*KTOP][IM] bf16
    __bf16* S = (__bf16*)GS;   // [TT][ISHD] bf16 (aliases G)

    hipMemsetAsync(counts, 0, EE * sizeof(int), stream);
    hipMemsetAsync(moeacc, 0, (size_t)TT * HH * sizeof(float), stream);

    cvtx_kernel<<<TT * HH / 1024, 256, 0, stream>>>(x, xb);
    router_kernel<<<TT, 256, 0, stream>>>(x, wr, wshg, out_logits,
                                          counts, topk_e, topk_slot, topk_w, sgate);
    scan_kernel<<<1, 64, 0, stream>>>(counts, offsets);
    scatter_kernel<<<(TT * KTOP + 255) / 256, 256, 0, stream>>>(
        offsets, topk_e, topk_slot, topk_w, tok_list, wlist);

    // experts: gate/up -> compact G (bf16). 1-D grid, XCD-chunk swizzled.
    gateup_kernel<<<dim3(8 * (IM / 64) * EE), 256, 0, stream>>>(
        xb, wg, wu, counts, offsets, tok_list, wlist, G, IM);

    // experts: down -> atomic accumulate into moeacc
    down_kernel<<<dim3(8 * (HH / 128) * EE), 256, 0, stream>>>(
        G, wd, counts, offsets, tok_list, moeacc);

    // shared expert gate/up -> S
    gateup_kernel<<<dim3(8 * (ISHD / 64)), 256, 0, stream>>>(
        xb, wsg, wsu, nullptr, nullptr, nullptr, nullptr, S, ISHD);

    // shared down + sigmoid gate + combine -> fp32 out
    shdown_kernel<<<dim3(8 * (HH / 64)), 256, 0, stream>>>(
        S, wsd, moeacc, sgate, out);
}

// Round 3
// 914.248 us; speedup vs baseline: 1.2185x; 1.2185x over previous
//
#include <hip/hip_runtime.h>
#include <hip/hip_bf16.h>
#include <cmath>

// Problem constants (Qwen2 MoE block)
#define TT   1024   // tokens
#define HH   2048   // hidden
#define EE   16     // experts
#define KTOP 4      // top-k
#define IM   1408   // moe intermediate
#define ISHD 5632   // shared intermediate
#define BK   64     // K-slice staged in LDS

typedef __bf16 bf16x8 __attribute__((ext_vector_type(8)));
typedef __bf16 bf16x4 __attribute__((ext_vector_type(4)));
typedef float  f32x4  __attribute__((ext_vector_type(4)));

__device__ inline bf16x4 cvt4(float4 f) {
    bf16x4 r;
    r[0] = (__bf16)f.x; r[1] = (__bf16)f.y; r[2] = (__bf16)f.z; r[3] = (__bf16)f.w;
    return r;
}

// ---------------------------------------------------------------------------
// Kernel 0: convert x fp32 -> bf16 once (A-side of all gate/up GEMMs)
// ---------------------------------------------------------------------------
__global__ __launch_bounds__(256) void cvtx_kernel(
    const float* __restrict__ x, __bf16* __restrict__ xb) {
    const int i = (blockIdx.x * 256 + threadIdx.x) * 4;
    *(bf16x4*)(xb + i) = cvt4(*(const float4*)(x + i));
}

// ---------------------------------------------------------------------------
// Kernel 1: router (fp32 exact). One block per token.
// ---------------------------------------------------------------------------
__global__ __launch_bounds__(256) void router_kernel(
    const float* __restrict__ x, const float* __restrict__ wr,
    const float* __restrict__ wshg,
    float* __restrict__ out_logits, int* __restrict__ counts,
    int* __restrict__ topk_e, int* __restrict__ topk_slot,
    float* __restrict__ topk_w, float* __restrict__ sgate)
{
    const int t    = blockIdx.x;
    const int tid  = threadIdx.x;
    const int wave = tid >> 6;
    const int lane = tid & 63;

    __shared__ float logits[EE];
    __shared__ float sgv;

    const float* xrow = x + (size_t)t * HH;
    float4 xv[4][2];
#pragma unroll
    for (int c = 0; c < 4; c++) {
        xv[c][0] = *(const float4*)(xrow + c * 512 + lane * 8);
        xv[c][1] = *(const float4*)(xrow + c * 512 + lane * 8 + 4);
    }

#pragma unroll
    for (int j = 0; j < 4; j++) {
        const int e = wave * 4 + j;
        const float* wrow = wr + (size_t)e * HH;
        float s = 0.f;
#pragma unroll
        for (int c = 0; c < 4; c++) {
            float4 w0 = *(const float4*)(wrow + c * 512 + lane * 8);
            float4 w1 = *(const float4*)(wrow + c * 512 + lane * 8 + 4);
            s += xv[c][0].x * w0.x + xv[c][0].y * w0.y + xv[c][0].z * w0.z + xv[c][0].w * w0.w;
            s += xv[c][1].x * w1.x + xv[c][1].y * w1.y + xv[c][1].z * w1.z + xv[c][1].w * w1.w;
        }
        for (int off = 32; off > 0; off >>= 1) s += __shfl_down(s, off, 64);
        if (lane == 0) logits[e] = s;
    }
    if (wave == 0) {
        float s = 0.f;
#pragma unroll
        for (int c = 0; c < 4; c++) {
            float4 w0 = *(const float4*)(wshg + c * 512 + lane * 8);
            float4 w1 = *(const float4*)(wshg + c * 512 + lane * 8 + 4);
            s += xv[c][0].x * w0.x + xv[c][0].y * w0.y + xv[c][0].z * w0.z + xv[c][0].w * w0.w;
            s += xv[c][1].x * w1.x + xv[c][1].y * w1.y + xv[c][1].z * w1.z + xv[c][1].w * w1.w;
        }
        for (int off = 32; off > 0; off >>= 1) s += __shfl_down(s, off, 64);
        if (lane == 0) sgv = s;
    }
    __syncthreads();

    if (tid == 0) {
        float mx = -1e30f;
        for (int e = 0; e < EE; e++) {
            out_logits[t * EE + e] = logits[e];
            mx = fmaxf(mx, logits[e]);
        }
        float p[EE]; float den = 0.f;
        for (int e = 0; e < EE; e++) { p[e] = expf(logits[e] - mx); den += p[e]; }
        const float inv = 1.f / den;
        bool used[EE];
        for (int e = 0; e < EE; e++) used[e] = false;
        for (int k = 0; k < KTOP; k++) {
            int best = 0; float bv = -1.f;
            for (int e = 0; e < EE; e++)
                if (!used[e] && p[e] > bv) { bv = p[e]; best = e; }
            used[best] = true;
            int slot = atomicAdd(&counts[best], 1);
            topk_e[t * KTOP + k]    = best;
            topk_slot[t * KTOP + k] = slot;
            topk_w[t * KTOP + k]    = bv * inv;   // fp32 unrounded
        }
        sgate[t] = 1.f / (1.f + expf(-sgv));
    }
}

__global__ void scan_kernel(const int* __restrict__ counts,
                            int* __restrict__ offsets) {
    if (threadIdx.x == 0 && blockIdx.x == 0) {
        int a = 0;
        for (int e = 0; e < EE; e++) { offsets[e] = a; a += counts[e]; }
        offsets[EE] = a;
    }
}

__global__ __launch_bounds__(256) void scatter_kernel(
    const int* __restrict__ offsets, const int* __restrict__ topk_e,
    const int* __restrict__ topk_slot, const float* __restrict__ topk_w,
    int* __restrict__ tok_list, float* __restrict__ wlist)
{
    const int i = blockIdx.x * 256 + threadIdx.x;
    if (i < TT * KTOP) {
        const int e   = topk_e[i];
        const int pos = offsets[e] + topk_slot[i];
        tok_list[pos] = i >> 2;
        wlist[pos]    = topk_w[i];
    }
}

// ---------------------------------------------------------------------------
// Kernel 2/4: gate+up dual GEMM. BM=128, BN=64, BK=64, LDS-staged,
// register-prefetch of next K-slice. Proven 890us structure; ONLY change:
// 1-D grid + chunked XCD swizzle with m-tile fastest, so the 8 blocks
// sharing a weight panel are consecutive origs -> same XCD L2
// (round-2 measured: FETCH_SIZE 512 -> 208 MB).
// ---------------------------------------------------------------------------
__global__ __launch_bounds__(256) void gateup_kernel(
    const __bf16* __restrict__ xb, const float* __restrict__ wgate,
    const float* __restrict__ wup, const int* __restrict__ counts,
    const int* __restrict__ offsets, const int* __restrict__ tok_list,
    const float* __restrict__ wlist, __bf16* __restrict__ Gout, const int I)
{
    // bijective chunked XCD swizzle (nwg % 8 == 0); decode m-tile fastest
    const int nwg   = gridDim.x;
    const int chunk = nwg >> 3;
    const int bid   = blockIdx.x;
    const int orig  = (bid & 7) * chunk + (bid >> 3);
    const int mt    = orig & 7;            // TT/128 = 8 m-tiles
    const int rest  = orig >> 3;
    const int NX    = I >> 6;              // I/64 n-tiles
    const int nt    = rest % NX;
    const int e     = rest / NX;

    const int Ne   = counts ? counts[e]  : TT;
    const int base = counts ? offsets[e] : 0;
    const int m0 = mt * 128;
    if (m0 >= Ne) return;
    const int n0 = nt * 64;

    __shared__ __bf16 As[128][72];
    __shared__ __bf16 Bgs[64][72];
    __shared__ __bf16 Bus[64][72];

    const int tid = threadIdx.x;
    // A staging: 32 rows/pass x (8 thr x 8 el), 4 passes
    const int arow = tid >> 3;
    const int acg  = tid & 7;
    const __bf16* aptr[4];
#pragma unroll
    for (int p = 0; p < 4; p++) {
        int sc  = min(m0 + p * 32 + arow, Ne - 1);
        int tok = tok_list ? tok_list[base + sc] : sc;
        aptr[p] = xb + (size_t)tok * HH + acg * 8;
    }
    // B staging: 16 rows/pass x (16 thr x float4), 4 passes
    const int brow = tid >> 4;
    const int bc4  = tid & 15;
    const float* bgptr[4];
    const float* buptr[4];
#pragma unroll
    for (int p = 0; p < 4; p++) {
        size_t off = ((size_t)e * I + n0 + p * 16 + brow) * HH + bc4 * 4;
        bgptr[p] = wgate + off;
        buptr[p] = wup   + off;
    }

    const int wave = tid >> 6, lane = tid & 63;
    const int wm = wave >> 1, wn = wave & 1;
    const int q = lane >> 4, r = lane & 15;

    f32x4 accg[4][2], accu[4][2];
#pragma unroll
    for (int i = 0; i < 4; i++)
#pragma unroll
        for (int j = 0; j < 2; j++) {
            accg[i][j] = (f32x4){0.f, 0.f, 0.f, 0.f};
            accu[i][j] = (f32x4){0.f, 0.f, 0.f, 0.f};
        }

    bf16x8 av[4]; float4 bgv[4], buv[4];
#pragma unroll
    for (int p = 0; p < 4; p++) {
        av[p]  = *(const bf16x8*)(aptr[p]);
        bgv[p] = *(const float4*)(bgptr[p]);
        buv[p] = *(const float4*)(buptr[p]);
    }

    for (int kk = 0; kk < HH; kk += BK) {
        __syncthreads();
#pragma unroll
        for (int p = 0; p < 4; p++) {
            *(bf16x8*)&As[p * 32 + arow][acg * 8]  = av[p];
            *(bf16x4*)&Bgs[p * 16 + brow][bc4 * 4] = cvt4(bgv[p]);
            *(bf16x4*)&Bus[p * 16 + brow][bc4 * 4] = cvt4(buv[p]);
        }
        __syncthreads();
        if (kk + BK < HH) {
            const int ko = kk + BK;
#pragma unroll
            for (int p = 0; p < 4; p++) {
                av[p]  = *(const bf16x8*)(aptr[p] + ko);
                bgv[p] = *(const float4*)(bgptr[p] + ko);
                buv[p] = *(const float4*)(buptr[p] + ko);
            }
        }
#pragma unroll
        for (int ks = 0; ks < BK; ks += 32) {
            bf16x8 af[4], bgf[2], buf[2];
#pragma unroll
            for (int i = 0; i < 4; i++)
                af[i] = *(const bf16x8*)&As[wm * 64 + i * 16 + r][ks + q * 8];
#pragma unroll
            for (int j = 0; j < 2; j++) {
                bgf[j] = *(const bf16x8*)&Bgs[wn * 32 + j * 16 + r][ks + q * 8];
                buf[j] = *(const bf16x8*)&Bus[wn * 32 + j * 16 + r][ks + q * 8];
            }
#pragma unroll
            for (int i = 0; i < 4; i++)
#pragma unroll
                for (int j = 0; j < 2; j++) {
                    accg[i][j] = __builtin_amdgcn_mfma_f32_16x16x32_bf16(af[i], bgf[j], accg[i][j], 0, 0, 0);
                    accu[i][j] = __builtin_amdgcn_mfma_f32_16x16x32_bf16(af[i], buf[j], accu[i][j], 0, 0, 0);
                }
        }
    }

#pragma unroll
    for (int i = 0; i < 4; i++)
#pragma unroll
        for (int reg = 0; reg < 4; reg++) {
            const int srow = m0 + wm * 64 + i * 16 + q * 4 + reg;
            if (srow < Ne) {
                const float w = wlist ? wlist[base + srow] : 1.f;
                __bf16* gp = Gout + (size_t)(base + srow) * I + n0 + wn * 32;
#pragma unroll
                for (int j = 0; j < 2; j++) {
                    float g = accg[i][j][reg];
                    float u = accu[i][j][reg];
                    float act = g / (1.f + expf(-g));
                    gp[j * 16 + r] = (__bf16)(act * u * w);
                }
            }
        }
}

// ---------------------------------------------------------------------------
// Kernel 3: expert down GEMM. BM=128, BN=128, BK=64, LDS-staged.
// A = compact G (bf16); B = wd rows (fp32->bf16). Epilogue: atomicAdd fp32.
// Only change vs proven structure: 1-D XCD-swizzled grid, m-tile fastest.
// ---------------------------------------------------------------------------
__global__ __launch_bounds__(256) void down_kernel(
    const __bf16* __restrict__ G, const float* __restrict__ wd,
    const int* __restrict__ counts, const int* __restrict__ offsets,
    const int* __restrict__ tok_list, float* __restrict__ moeacc)
{
    const int nwg   = gridDim.x;           // 2048
    const int chunk = nwg >> 3;
    const int bid   = blockIdx.x;
    const int orig  = (bid & 7) * chunk + (bid >> 3);
    const int mt    = orig & 7;            // 8 m-tiles
    const int rest  = orig >> 3;
    const int nt    = rest & 15;           // HH/128 = 16
    const int e     = rest >> 4;

    const int Ne   = counts[e];
    const int base = offsets[e];
    const int m0 = mt * 128;
    if (m0 >= Ne) return;
    const int n0 = nt * 128;

    __shared__ __bf16 As[128][72];
    __shared__ __bf16 Bs[128][72];

    const int tid = threadIdx.x;
    const int arow = tid >> 3;
    const int acg  = tid & 7;
    const __bf16* aptr[4];
#pragma unroll
    for (int p = 0; p < 4; p++) {
        int sc = min(m0 + p * 32 + arow, Ne - 1);
        aptr[p] = G + (size_t)(base + sc) * IM + acg * 8;
    }
    const int brow = tid >> 4;
    const int bc4  = tid & 15;
    const float* bptr[8];
#pragma unroll
    for (int p = 0; p < 8; p++)
        bptr[p] = wd + ((size_t)e * HH + n0 + p * 16 + brow) * IM + bc4 * 4;

    const int wave = tid >> 6, lane = tid & 63;
    const int wm = wave >> 1, wn = wave & 1;
    const int q = lane >> 4, r = lane & 15;

    f32x4 acc[4][4];
#pragma unroll
    for (int i = 0; i < 4; i++)
#pragma unroll
        for (int j = 0; j < 4; j++) acc[i][j] = (f32x4){0.f, 0.f, 0.f, 0.f};

    bf16x8 av[4]; float4 bv[8];
#pragma unroll
    for (int p = 0; p < 4; p++) av[p] = *(const bf16x8*)(aptr[p]);
#pragma unroll
    for (int p = 0; p < 8; p++) bv[p] = *(const float4*)(bptr[p]);

    for (int kk = 0; kk < IM; kk += BK) {
        __syncthreads();
#pragma unroll
        for (int p = 0; p < 4; p++)
            *(bf16x8*)&As[p * 32 + arow][acg * 8] = av[p];
#pragma unroll
        for (int p = 0; p < 8; p++)
            *(bf16x4*)&Bs[p * 16 + brow][bc4 * 4] = cvt4(bv[p]);
        __syncthreads();
        if (kk + BK < IM) {
            const int ko = kk + BK;
#pragma unroll
            for (int p = 0; p < 4; p++) av[p] = *(const bf16x8*)(aptr[p] + ko);
#pragma unroll
            for (int p = 0; p < 8; p++) bv[p] = *(const float4*)(bptr[p] + ko);
        }
#pragma unroll
        for (int ks = 0; ks < BK; ks += 32) {
            bf16x8 af[4], bf[4];
#pragma unroll
            for (int i = 0; i < 4; i++)
                af[i] = *(const bf16x8*)&As[wm * 64 + i * 16 + r][ks + q * 8];
#pragma unroll
            for (int j = 0; j < 4; j++)
                bf[j] = *(const bf16x8*)&Bs[wn * 64 + j * 16 + r][ks + q * 8];
#pragma unroll
            for (int i = 0; i < 4; i++)
#pragma unroll
                for (int j = 0; j < 4; j++)
                    acc[i][j] = __builtin_amdgcn_mfma_f32_16x16x32_bf16(af[i], bf[j], acc[i][j], 0, 0, 0);
        }
    }

#pragma unroll
    for (int i = 0; i < 4; i++)
#pragma unroll
        for (int reg = 0; reg < 4; reg++) {
            const int srow = m0 + wm * 64 + i * 16 + q * 4 + reg;
            if (srow < Ne) {
                const int tok = tok_list[base + srow];
                float* mp = moeacc + (size_t)tok * HH + n0 + wn * 64;
#pragma unroll
                for (int j = 0; j < 4; j++)
                    atomicAdd(mp + j * 16 + r, acc[i][j][reg]);
            }
        }
}

// ---------------------------------------------------------------------------
// Kernel 5: shared down + sigmoid gate + combine. BM=128, BN=64, BK=64.
// Only change vs proven structure: 1-D XCD-swizzled grid, m-tile fastest.
// ---------------------------------------------------------------------------
__global__ __launch_bounds__(256) void shdown_kernel(
    const __bf16* __restrict__ S, const float* __restrict__ wsd,
    const float* __restrict__ moeacc, const float* __restrict__ sgate,
    float* __restrict__ out)
{
    const int nwg   = gridDim.x;           // 256
    const int chunk = nwg >> 3;
    const int bid   = blockIdx.x;
    const int orig  = (bid & 7) * chunk + (bid >> 3);
    const int mt    = orig & 7;
    const int nt    = orig >> 3;           // HH/64 = 32

    const int m0 = mt * 128;
    const int n0 = nt * 64;

    __shared__ __bf16 As[128][72];
    __shared__ __bf16 Bs[64][72];

    const int tid = threadIdx.x;
    const int arow = tid >> 3;
    const int acg  = tid & 7;
    const __bf16* aptr[4];
#pragma unroll
    for (int p = 0; p < 4; p++)
        aptr[p] = S + (size_t)(m0 + p * 32 + arow) * ISHD + acg * 8;
    const int brow = tid >> 4;
    const int bc4  = tid & 15;
    const float* bptr[4];
#pragma unroll
    for (int p = 0; p < 4; p++)
        bptr[p] = wsd + (size_t)(n0 + p * 16 + brow) * ISHD + bc4 * 4;

    const int wave = tid >> 6, lane = tid & 63;
    const int wm = wave >> 1, wn = wave & 1;
    const int q = lane >> 4, r = lane & 15;

    f32x4 acc[4][2];
#pragma unroll
    for (int i = 0; i < 4; i++)
#pragma unroll
        for (int j = 0; j < 2; j++) acc[i][j] = (f32x4){0.f, 0.f, 0.f, 0.f};

    bf16x8 av[4]; float4 bv[4];
#pragma unroll
    for (int p = 0; p < 4; p++) {
        av[p] = *(const bf16x8*)(aptr[p]);
        bv[p] = *(const float4*)(bptr[p]);
    }

    for (int kk = 0; kk < ISHD; kk += BK) {
        __syncthreads();
#pragma unroll
        for (int p = 0; p < 4; p++) {
            *(bf16x8*)&As[p * 32 + arow][acg * 8]  = av[p];
            *(bf16x4*)&Bs[p * 16 + brow][bc4 * 4] = cvt4(bv[p]);
        }
        __syncthreads();
        if (kk + BK < ISHD) {
            const int ko = kk + BK;
#pragma unroll
            for (int p = 0; p < 4; p++) {
                av[p] = *(const bf16x8*)(aptr[p] + ko);
                bv[p] = *(const float4*)(bptr[p] + ko);
            }
        }
#pragma unroll
        for (int ks = 0; ks < BK; ks += 32) {
            bf16x8 af[4], bf[2];
#pragma unroll
            for (int i = 0; i < 4; i++)
                af[i] = *(const bf16x8*)&As[wm * 64 + i * 16 + r][ks + q * 8];
#pragma unroll
            for (int j = 0; j < 2; j++)
                bf[j] = *(const bf16x8*)&Bs[wn * 32 + j * 16 + r][ks + q * 8];
#pragma unroll
            for (int i = 0; i < 4; i++)
#pragma unroll
                for (int j = 0; j < 2; j++)
                    acc[i][j] = __builtin_amdgcn_mfma_f32_16x16x32_bf16(af[i], bf[j], acc[i][j], 0, 0, 0);
        }
    }

#pragma unroll
    for (int i = 0; i < 4; i++)
#pragma unroll
        for (int reg = 0; reg < 4; reg++) {
            const int t  = m0 + wm * 64 + i * 16 + q * 4 + reg;
            const float sg = sgate[t];
            const float* mp = moeacc + (size_t)t * HH + n0 + wn * 32;
            float* op = out + (size_t)t * HH + n0 + wn * 32;
#pragma unroll
            for (int j = 0; j < 2; j++)
                op[j * 16 + r] = mp[j * 16 + r] + sg * acc[i][j][reg];
        }
}

// ---------------------------------------------------------------------------
extern "C" void kernel_launch(void* const* d_in, const int* in_sizes, int n_in,
                              void* d_out, int out_size, void* d_ws, size_t ws_size,
                              hipStream_t stream) {
    const float* x    = (const float*)d_in[0];
    const float* wr   = (const float*)d_in[1];
    const float* wg   = (const float*)d_in[2];
    const float* wu   = (const float*)d_in[3];
    const float* wd   = (const float*)d_in[4];
    const float* wsg  = (const float*)d_in[5];
    const float* wsu  = (const float*)d_in[6];
    const float* wsd  = (const float*)d_in[7];
    const float* wshg = (const float*)d_in[8];

    float* out        = (float*)d_out;
    float* out_logits = out + (size_t)TT * HH;

    // workspace layout (~23.1 MiB; G and S alias: G dies before S is born)
    char* ws = (char*)d_ws;
    int*    counts    = (int*)(ws + 0);
    int*    offsets   = (int*)(ws + 256);
    int*    topk_e    = (int*)(ws + 512);
    int*    topk_slot = (int*)(ws + 512 + 16384);
    float*  topk_w    = (float*)(ws + 512 + 32768);
    float*  sgate     = (float*)(ws + 512 + 49152);
    int*    tok_list  = (int*)(ws + 512 + 53248);
    float*  wlist     = (float*)(ws + 512 + 69632);
    __bf16* xb        = (__bf16*)(ws + 86528);                 // 4 MB [TT][HH] bf16
    float*  moeacc    = (float*)(ws + 86528 + 4194304);        // 8 MB [TT][HH] f32
    char*   GS        = (char*)moeacc + (size_t)TT * HH * 4;   // 11.5 MB
    __bf16* G = (__bf16*)GS;   // compact [TT*KTOP][IM] bf16
    __bf16* S = (__bf16*)GS;   // [TT][ISHD] bf16 (aliases G)

    hipMemsetAsync(counts, 0, EE * sizeof(int), stream);
    hipMemsetAsync(moeacc, 0, (size_t)TT * HH * sizeof(float), stream);

    cvtx_kernel<<<TT * HH / 1024, 256, 0, stream>>>(x, xb);
    router_kernel<<<TT, 256, 0, stream>>>(x, wr, wshg, out_logits,
                                          counts, topk_e, topk_slot, topk_w, sgate);
    scan_kernel<<<1, 64, 0, stream>>>(counts, offsets);
    scatter_kernel<<<(TT * KTOP + 255) / 256, 256, 0, stream>>>(
        offsets, topk_e, topk_slot, topk_w, tok_list, wlist);

    // experts: gate/up -> compact G (bf16). 1-D grid, XCD-chunk swizzled.
    gateup_kernel<<<dim3(8 * (IM / 64) * EE), 256, 0, stream>>>(
        xb, wg, wu, counts, offsets, tok_list, wlist, G, IM);

    // experts: down -> atomic accumulate into moeacc
    down_kernel<<<dim3(8 * (HH / 128) * EE), 256, 0, stream>>>(
        G, wd, counts, offsets, tok_list, moeacc);

    // shared expert gate/up -> S
    gateup_kernel<<<dim3(8 * (ISHD / 64)), 256, 0, stream>>>(
        xb, wsg, wsu, nullptr, nullptr, nullptr, nullptr, S, ISHD);

    // shared down + sigmoid gate + combine -> fp32 out
    shdown_kernel<<<dim3(8 * (HH / 64)), 256, 0, stream>>>(
        S, wsd, moeacc, sgate, out);
}